// Round 9
// baseline (33.045 us; speedup 1.0000x reference)
//
#include <hip/hip_runtime.h>
#include <math.h>

#define B_ 512
#define I_ 512
#define O_ 512
#define BO_ (B_*O_)
#define IO_ (I_*O_)

// fast path (kanR): 64b x 64o x 16i blocks, thread = 4b x 4o
#define ZR 32                  // i-splits
#define KIR 16                 // i per block (one chunk)

// legacy kanZ fallback tiling
#define TB 64
#define TO 16
#define KI 16
#define ZN 8
#define NIZ (I_/ZN)
#define NCHZ (NIZ/KI)
#define LXS (TB + 4)
#define NCH (I_/KI)

#define SQH    0.84932180028801904f   // sqrt(0.5*log2(e))
#define MN_   (-1.2023679775792928f)  // -(2 ln2) * NORM
#define NN_   (-0.86732507058407750f) // -NORM
#define BN_EPS (1e-5f)

#if defined(__has_builtin)
#if __has_builtin(__builtin_amdgcn_exp2f)
#define EXP2F(v) __builtin_amdgcn_exp2f(v)
#endif
#if __has_builtin(__builtin_amdgcn_global_load_lds)
#define HAVE_DMA 1
#endif
#endif
#ifndef EXP2F
#define EXP2F(v) exp2f(v)
#endif

#ifdef HAVE_DMA
__device__ __forceinline__ void dma16(const void* g, void* l) {
    __builtin_amdgcn_global_load_lds(
        (const __attribute__((address_space(1))) void*)g,
        (__attribute__((address_space(3))) void*)l, 16, 0, 0);
}
#endif

// ---------------------------------------------------------------------------
// K0: pack params into pp[i][o] = {c, g, m, n} (float4) and transpose x into
// xT[i][b]. Blocks [0,1024) do pp elementwise; [1024,1088) do xT.
// ---------------------------------------------------------------------------
__global__ __launch_bounds__(256) void pack_px(
    const float* __restrict__ x, const float* __restrict__ scale,
    const float* __restrict__ bias, const float* __restrict__ weight,
    float4* __restrict__ pp, float* __restrict__ xT)
{
    const int bid = blockIdx.x;
    const int t   = threadIdx.x;

    if (bid < IO_ / 256) {
        const int g = bid * 256 + t;
        const float sc = scale[g];
        const float bi = bias[g];
        const float w  = weight[g];
        const float c  = SQH * __builtin_amdgcn_rcpf(sc);
        pp[g] = make_float4(c, -bi * c, MN_ * w, NN_ * w);
    } else {
        __shared__ float T[64][68];
        const int tile = bid - IO_ / 256;      // 0..63
        const int i0 = (tile & 7) * 64;
        const int b0 = (tile >> 3) * 64;
        const int r  = t >> 4;                 // 0..15
        const int c4 = (t & 15) * 4;           // 0..60
        #pragma unroll
        for (int p = 0; p < 4; ++p) {
            const int b = b0 + r + p * 16;
            const float4 v = *reinterpret_cast<const float4*>(&x[(size_t)b * I_ + i0 + c4]);
            T[c4 + 0][r + p * 16] = v.x;
            T[c4 + 1][r + p * 16] = v.y;
            T[c4 + 2][r + p * 16] = v.z;
            T[c4 + 3][r + p * 16] = v.w;
        }
        __syncthreads();
        #pragma unroll
        for (int p = 0; p < 4; ++p) {
            const int il = r + p * 16;
            const float4 v = *reinterpret_cast<const float4*>(&T[il][c4]);
            *reinterpret_cast<float4*>(&xT[(size_t)(i0 + il) * B_ + b0 + c4]) = v;
        }
    }
}

#ifdef HAVE_DMA
// ---------------------------------------------------------------------------
// K1 (fast): 4b x 4o register-blocked partial KAN sums. 2048 blocks x 256
// threads; block = 64b x 64o x 16i; thread owns 4b x 4o. Single-buffer LDS
// (20.5 KB -> 8 blocks/CU = 32 waves/CU), DMA prologue (zero staging regs),
// ONE barrier per block. LDS: 5 x ds_read_b128 per 16 evals = 5 B/eval.
// fid&7 = o-tile => XCD k owns o in [64k,64k+64) (pp/pY slices L2-resident).
// ---------------------------------------------------------------------------
__global__ __launch_bounds__(256) void kanR(
    const float4* __restrict__ pp, const float* __restrict__ xT,
    float* __restrict__ pY)
{
    __shared__ float4 Lp[KIR][64];     // [i][o] {c,g,m,n}  16 KB (linear DMA dest)
    __shared__ float  Lx[KIR][64];     // [i][b]             4 KB (linear DMA dest)

    const int fid  = blockIdx.x;
    const int ot   = fid & 7;              // XCD-owned o-tile (64 o)
    const int rest = fid >> 3;
    const int bt   = rest & 7;             // 8 b-tiles of 64
    const int iz   = rest >> 3;            // 0..31

    const int o0 = ot * 64;
    const int b0 = bt * 64;
    const int i0 = iz * KIR;

    const int t  = threadIdx.x;
    const int oq = t & 15;                 // o-quad (eval)
    const int bq = t >> 4;                 // b-quad (eval)
    const int wv = t >> 6;                 // wave id (uniform)
    const int l  = t & 63;                 // lane

    // --- DMA prologue: params (4 calls/wave) + x (1 call/wave) ---
    #pragma unroll
    for (int k = 0; k < 4; ++k) {
        dma16(&pp[(size_t)(i0 + wv * 4 + k) * O_ + o0 + l],
              (char*)&Lp[0][0] + wv * 4096 + k * 1024);
    }
    dma16(&xT[(size_t)(i0 + wv * 4 + (l >> 4)) * B_ + b0 + (l & 15) * 4],
          (char*)&Lx[0][0] + wv * 1024);

    __syncthreads();                       // drains the DMA (vmcnt in barrier)

    float4 acc0 = {0,0,0,0}, acc1 = {0,0,0,0}, acc2 = {0,0,0,0}, acc3 = {0,0,0,0};

#define EVQ(xs, A)                                                           \
    {                                                                        \
        { const float h  = fmaf((xs), p0.x, p0.y);                           \
          const float un = -h * h;                                           \
          const float e  = EXP2F(un);                                        \
          const float gg = fmaf(un, p0.z, p0.w);                             \
          A.x = fmaf(gg, e, A.x); }                                          \
        { const float h  = fmaf((xs), p1.x, p1.y);                           \
          const float un = -h * h;                                           \
          const float e  = EXP2F(un);                                        \
          const float gg = fmaf(un, p1.z, p1.w);                             \
          A.y = fmaf(gg, e, A.y); }                                          \
        { const float h  = fmaf((xs), p2.x, p2.y);                           \
          const float un = -h * h;                                           \
          const float e  = EXP2F(un);                                        \
          const float gg = fmaf(un, p2.z, p2.w);                             \
          A.z = fmaf(gg, e, A.z); }                                          \
        { const float h  = fmaf((xs), p3.x, p3.y);                           \
          const float un = -h * h;                                           \
          const float e  = EXP2F(un);                                        \
          const float gg = fmaf(un, p3.z, p3.w);                             \
          A.w = fmaf(gg, e, A.w); }                                          \
    }

    #pragma unroll 4
    for (int ii = 0; ii < KIR; ++ii) {
        const float4 x4 = *reinterpret_cast<const float4*>(&Lx[ii][bq * 4]);
        const float4 p0 = Lp[ii][oq * 4 + 0];
        const float4 p1 = Lp[ii][oq * 4 + 1];
        const float4 p2 = Lp[ii][oq * 4 + 2];
        const float4 p3 = Lp[ii][oq * 4 + 3];
        EVQ(x4.x, acc0);
        EVQ(x4.y, acc1);
        EVQ(x4.z, acc2);
        EVQ(x4.w, acc3);
    }
#undef EVQ

    const size_t base = ((size_t)iz * B_ + b0 + bq * 4) * O_ + o0 + oq * 4;
    *reinterpret_cast<float4*>(&pY[base + 0 * O_]) = acc0;
    *reinterpret_cast<float4*>(&pY[base + 1 * O_]) = acc1;
    *reinterpret_cast<float4*>(&pY[base + 2 * O_]) = acc2;
    *reinterpret_cast<float4*>(&pY[base + 3 * O_]) = acc3;
}
#endif // HAVE_DMA

// ---------------------------------------------------------------------------
// kanZ (proven R7 kernel) — fallback if DMA builtin unavailable.
// ---------------------------------------------------------------------------
__global__ __launch_bounds__(256) void kanZ(
    const float* __restrict__ x, const float* __restrict__ scale,
    const float* __restrict__ bias, const float* __restrict__ weight,
    float* __restrict__ pY)
{
    __shared__ float Lx[KI][LXS];
    __shared__ float Lp[KI][TO][4];

    const int fid = blockIdx.x;
    const int xcd = fid & 7;
    const int seq = fid >> 3;
    const int ot  = xcd * 4 + (seq & 3);
    const int by  = (seq >> 2) & 7;
    const int iz  = seq >> 5;

    const int o0 = ot * TO;
    const int b0 = by * TB;
    const int z0 = iz * NIZ;

    const int t   = threadIdx.x;
    const int to  = t & (TO - 1);
    const int tb4 = t >> 4;
    const int lb  = t >> 2;
    const int lq  = t & 3;
    const int li  = t >> 4;
    const int lo  = t & 15;

    float acc0 = 0.f, acc1 = 0.f, acc2 = 0.f, acc3 = 0.f;

    for (int ch = 0; ch < NCHZ; ++ch) {
        const int i0 = z0 + ch * KI;
        const float4 xv = *reinterpret_cast<const float4*>(
            &x[(size_t)(b0 + lb) * I_ + i0 + lq * 4]);
        const int pidx = (i0 + li) * O_ + o0 + lo;
        const float sc = scale[pidx];
        const float bi = bias[pidx];
        const float w  = weight[pidx];

        __syncthreads();
        Lx[lq * 4 + 0][lb] = xv.x;
        Lx[lq * 4 + 1][lb] = xv.y;
        Lx[lq * 4 + 2][lb] = xv.z;
        Lx[lq * 4 + 3][lb] = xv.w;
        const float c = SQH * __builtin_amdgcn_rcpf(sc);
        Lp[li][lo][0] = c;
        Lp[li][lo][1] = -bi * c;
        Lp[li][lo][2] = MN_ * w;
        Lp[li][lo][3] = NN_ * w;
        __syncthreads();

        #pragma unroll
        for (int ii = 0; ii < KI; ++ii) {
            const float4 p  = *reinterpret_cast<const float4*>(&Lp[ii][to][0]);
            const float4 x4 = *reinterpret_cast<const float4*>(&Lx[ii][tb4 * 4]);
            {
                const float h  = fmaf(x4.x, p.x, p.y);
                const float un = -h * h;
                const float e  = EXP2F(un);
                const float gg = fmaf(un, p.z, p.w);
                acc0 = fmaf(gg, e, acc0);
            }
            {
                const float h  = fmaf(x4.y, p.x, p.y);
                const float un = -h * h;
                const float e  = EXP2F(un);
                const float gg = fmaf(un, p.z, p.w);
                acc1 = fmaf(gg, e, acc1);
            }
            {
                const float h  = fmaf(x4.z, p.x, p.y);
                const float un = -h * h;
                const float e  = EXP2F(un);
                const float gg = fmaf(un, p.z, p.w);
                acc2 = fmaf(gg, e, acc2);
            }
            {
                const float h  = fmaf(x4.w, p.x, p.y);
                const float un = -h * h;
                const float e  = EXP2F(un);
                const float gg = fmaf(un, p.z, p.w);
                acc3 = fmaf(gg, e, acc3);
            }
        }
    }

    const size_t base = ((size_t)iz * B_ + b0 + tb4 * 4) * O_ + o0 + to;
    pY[base + 0 * O_] = acc0;
    pY[base + 1 * O_] = acc1;
    pY[base + 2 * O_] = acc2;
    pY[base + 3 * O_] = acc3;
}

// ---------------------------------------------------------------------------
// K2: fused NZ-partial combine + BatchNorm stats + apply. 128 blocks, 4 o's
// each; o<->XCD mapping matches the producer so pY reads hit the local L2.
// ---------------------------------------------------------------------------
template <int NZ>
__global__ __launch_bounds__(256) void comb_bn(
    const float* __restrict__ pY,
    const float* __restrict__ gamma, const float* __restrict__ beta,
    float* __restrict__ y)
{
    __shared__ float Ws[4][8];
    __shared__ float Ac[8];

    const int bid = blockIdx.x;                       // 0..127
    const int o4  = (bid & 7) * 64 + (bid >> 3) * 4;  // XCD k owns o [64k,64k+64)
    const int t   = threadIdx.x;

    float4 v[2];
    float sx = 0.f, sy = 0.f, sz = 0.f, sw = 0.f;
    float qx = 0.f, qy = 0.f, qz = 0.f, qw = 0.f;
    #pragma unroll
    for (int r = 0; r < 2; ++r) {
        const int b = t + 256 * r;
        const size_t base = (size_t)b * O_ + o4;
        float4 a = *reinterpret_cast<const float4*>(&pY[base]);
        #pragma unroll
        for (int z = 1; z < NZ; ++z) {
            const float4 p = *reinterpret_cast<const float4*>(&pY[(size_t)z * BO_ + base]);
            a.x += p.x; a.y += p.y; a.z += p.z; a.w += p.w;
        }
        v[r] = a;
        sx += a.x; sy += a.y; sz += a.z; sw += a.w;
        qx += a.x * a.x; qy += a.y * a.y; qz += a.z * a.z; qw += a.w * a.w;
    }

    #pragma unroll
    for (int m = 1; m < 64; m <<= 1) {
        sx += __shfl_xor(sx, m); sy += __shfl_xor(sy, m);
        sz += __shfl_xor(sz, m); sw += __shfl_xor(sw, m);
        qx += __shfl_xor(qx, m); qy += __shfl_xor(qy, m);
        qz += __shfl_xor(qz, m); qw += __shfl_xor(qw, m);
    }
    if ((t & 63) == 0) {
        const int wv = t >> 6;
        Ws[wv][0] = sx; Ws[wv][1] = sy; Ws[wv][2] = sz; Ws[wv][3] = sw;
        Ws[wv][4] = qx; Ws[wv][5] = qy; Ws[wv][6] = qz; Ws[wv][7] = qw;
    }
    __syncthreads();
    if (t < 4) {
        const float s  = Ws[0][t]     + Ws[1][t]     + Ws[2][t]     + Ws[3][t];
        const float q  = Ws[0][t + 4] + Ws[1][t + 4] + Ws[2][t + 4] + Ws[3][t + 4];
        const float mean = s * (1.0f / B_);
        const float var  = q * (1.0f / B_) - mean * mean;
        const float inv  = rsqrtf(var + BN_EPS);
        const float a = gamma[o4 + t] * inv;
        Ac[t]     = a;
        Ac[t + 4] = fmaf(-mean, a, beta[o4 + t]);
    }
    __syncthreads();

    const float4 a4 = *reinterpret_cast<const float4*>(&Ac[0]);
    const float4 c4 = *reinterpret_cast<const float4*>(&Ac[4]);
    #pragma unroll
    for (int r = 0; r < 2; ++r) {
        const int b = t + 256 * r;
        float4 o;
        o.x = fmaf(v[r].x, a4.x, c4.x);
        o.y = fmaf(v[r].y, a4.y, c4.y);
        o.z = fmaf(v[r].z, a4.z, c4.z);
        o.w = fmaf(v[r].w, a4.w, c4.w);
        *reinterpret_cast<float4*>(&y[(size_t)b * O_ + o4]) = o;
    }
}

// ---------------------------------------------------------------------------

extern "C" void kernel_launch(void* const* d_in, const int* in_sizes, int n_in,
                              void* d_out, int out_size, void* d_ws, size_t ws_size,
                              hipStream_t stream) {
    const float* x      = (const float*)d_in[0];
    const float* scale  = (const float*)d_in[1];
    const float* bias   = (const float*)d_in[2];
    const float* weight = (const float*)d_in[3];
    const float* gamma  = (const float*)d_in[4];
    const float* beta   = (const float*)d_in[5];
    float* out = (float*)d_out;

    const size_t pYR_b = (size_t)ZR * BO_ * sizeof(float);    // 32 MB
    const size_t pp_b  = (size_t)IO_ * sizeof(float4);        // 4 MB
    const size_t xT_b  = (size_t)B_ * I_ * sizeof(float);     // 1 MB
    const size_t needR = pYR_b + pp_b + xT_b;                 // 37 MB
    const size_t pYZ_b = (size_t)ZN * BO_ * sizeof(float);    // 8 MB

#ifdef HAVE_DMA
    if (ws_size >= needR) {
        float*  pY = (float*)d_ws;
        float4* pp = (float4*)((char*)d_ws + pYR_b);
        float*  xT = (float*)((char*)d_ws + pYR_b + pp_b);

        pack_px<<<IO_ / 256 + 64, 256, 0, stream>>>(x, scale, bias, weight, pp, xT);
        kanR<<<8 * 8 * ZR, 256, 0, stream>>>(pp, xT, pY);              // 2048 blocks
        comb_bn<ZR><<<O_ / 4, 256, 0, stream>>>(pY, gamma, beta, out); // 128 blocks
        return;
    }
#endif
    if (ws_size >= pYZ_b) {
        float* pY = (float*)d_ws;
        kanZ<<<32 * 8 * 8, 256, 0, stream>>>(x, scale, bias, weight, pY);
        comb_bn<ZN><<<O_ / 4, 256, 0, stream>>>(pY, gamma, beta, out);
    }
    // (harness ws is always >= 8 MB in practice; no smaller path needed)
}

// Round 10
// 32.915 us; speedup vs baseline: 1.0040x; 1.0040x over previous
//
#include <hip/hip_runtime.h>
#include <math.h>

#define B_ 512
#define I_ 512
#define O_ 512
#define BO_ (B_*O_)
#define IO_ (I_*O_)

// fast path (kanT): block = 128b x 64o x 16i, thread = 8b x 4o
#define ZT 32                  // i-splits
#define KIT 16                 // i per block

// legacy kanZ fallback tiling
#define TB 64
#define TO 16
#define KI 16
#define ZN 8
#define NIZ (I_/ZN)
#define NCHZ (NIZ/KI)
#define LXS (TB + 4)

#define SQH    0.84932180028801904f   // sqrt(0.5*log2(e))
#define MN_   (-1.2023679775792928f)  // -(2 ln2) * NORM
#define NN_   (-0.86732507058407750f) // -NORM
#define BN_EPS (1e-5f)

#if defined(__has_builtin)
#if __has_builtin(__builtin_amdgcn_exp2f)
#define EXP2F(v) __builtin_amdgcn_exp2f(v)
#endif
#if __has_builtin(__builtin_amdgcn_global_load_lds)
#define HAVE_DMA 1
#endif
#endif
#ifndef EXP2F
#define EXP2F(v) exp2f(v)
#endif

#ifdef HAVE_DMA
__device__ __forceinline__ void dma16(const void* g, void* l) {
    __builtin_amdgcn_global_load_lds(
        (const __attribute__((address_space(1))) void*)g,
        (__attribute__((address_space(3))) void*)l, 16, 0, 0);
}
#endif

// ---------------------------------------------------------------------------
// K0: pack params into k-major swizzled planes
//   ppS[((i*8 + ot)*4 + k)*16 + o4] = {c, g, m, n} for o = ot*64 + o4*4 + k
// and transpose x into xT[i][b]. Blocks [0,1024) do ppS; [1024,1088) do xT.
// ---------------------------------------------------------------------------
__global__ __launch_bounds__(256) void pack_px(
    const float* __restrict__ x, const float* __restrict__ scale,
    const float* __restrict__ bias, const float* __restrict__ weight,
    float4* __restrict__ ppS, float* __restrict__ xT)
{
    const int bid = blockIdx.x;
    const int t   = threadIdx.x;

    if (bid < IO_ / 256) {
        const int g  = bid * 256 + t;
        const int i  = g >> 9;
        const int o  = g & 511;
        const int ot = o >> 6;
        const int ol = o & 63;
        const float sc = scale[g];
        const float bi = bias[g];
        const float w  = weight[g];
        const float c  = SQH * __builtin_amdgcn_rcpf(sc);
        const size_t idx = ((size_t)(i * 8 + ot) * 4 + (ol & 3)) * 16 + (ol >> 2);
        ppS[idx] = make_float4(c, -bi * c, MN_ * w, NN_ * w);
    } else {
        __shared__ float T[64][68];
        const int tile = bid - IO_ / 256;      // 0..63
        const int i0 = (tile & 7) * 64;
        const int b0 = (tile >> 3) * 64;
        const int r  = t >> 4;                 // 0..15
        const int c4 = (t & 15) * 4;           // 0..60
        #pragma unroll
        for (int p = 0; p < 4; ++p) {
            const int b = b0 + r + p * 16;
            const float4 v = *reinterpret_cast<const float4*>(&x[(size_t)b * I_ + i0 + c4]);
            T[c4 + 0][r + p * 16] = v.x;
            T[c4 + 1][r + p * 16] = v.y;
            T[c4 + 2][r + p * 16] = v.z;
            T[c4 + 3][r + p * 16] = v.w;
        }
        __syncthreads();
        #pragma unroll
        for (int p = 0; p < 4; ++p) {
            const int il = r + p * 16;
            const float4 v = *reinterpret_cast<const float4*>(&T[il][c4]);
            *reinterpret_cast<float4*>(&xT[(size_t)(i0 + il) * B_ + b0 + c4]) = v;
        }
    }
}

#ifdef HAVE_DMA
// ---------------------------------------------------------------------------
// K1 (fast): 8b x 4o register-blocked partial KAN sums, conflict-free LDS.
// 1024 blocks x 256 threads; block = 128b x 64o x 16i. DMA prologue (zero
// staging regs), ONE barrier. Param reads: k-major planes -> 16 lanes read
// contiguous 256B (2 lanes/bank, free). x reads: 4-address broadcast.
// 6 ds_read_b128 per 32 evals = 3 B/eval. fid&7 = o-tile = XCD owner.
// ---------------------------------------------------------------------------
__global__ __launch_bounds__(256) void kanT(
    const float4* __restrict__ ppS, const float* __restrict__ xT,
    float* __restrict__ pY)
{
    __shared__ float4 Lp[KIT][64];     // [i][k*16+o4] {c,g,m,n}  16 KB
    __shared__ float  Lx[KIT][128];    // [i][b]                   8 KB

    const int fid = blockIdx.x;
    const int ot  = fid & 7;               // XCD-owned o-tile (64 o)
    const int bt  = (fid >> 3) & 3;        // 4 b-tiles of 128
    const int iz  = fid >> 5;              // 0..31

    const int o0 = ot * 64;
    const int b0 = bt * 128;
    const int i0 = iz * KIT;

    const int t  = threadIdx.x;
    const int oq = t & 15;                 // o-quad (o = o0 + oq*4 + k)
    const int bq = t >> 4;                 // b-octet (b = b0 + bq*8 + r)
    const int wv = t >> 6;                 // wave id (uniform)
    const int l  = t & 63;                 // lane

    // --- DMA prologue ---
    // params: 16 KB, LDS rows of 1 KB; wave wv covers i-rows wv*4..wv*4+3
    #pragma unroll
    for (int k4 = 0; k4 < 4; ++k4) {
        dma16(&ppS[((size_t)(i0 + wv * 4 + k4) * 8 + ot) * 64 + l],
              (char*)&Lp[0][0] + wv * 4096 + k4 * 1024);
    }
    // x: 8 KB, LDS rows of 512B; each 1KB call covers 2 i-rows
    #pragma unroll
    for (int j = 0; j < 2; ++j) {
        dma16(&xT[(size_t)(i0 + wv * 4 + j * 2 + (l >> 5)) * B_ + b0 + (l & 31) * 4],
              (char*)&Lx[0][0] + wv * 2048 + j * 1024);
    }

    __syncthreads();                       // drains the DMA

    float4 a[8];
    #pragma unroll
    for (int r = 0; r < 8; ++r) a[r] = make_float4(0.f, 0.f, 0.f, 0.f);

#define EVQ(xs, A)                                                           \
    {                                                                        \
        { const float h  = fmaf((xs), p0.x, p0.y);                           \
          const float un = -h * h;                                           \
          const float e  = EXP2F(un);                                        \
          const float gg = fmaf(un, p0.z, p0.w);                             \
          A.x = fmaf(gg, e, A.x); }                                          \
        { const float h  = fmaf((xs), p1.x, p1.y);                           \
          const float un = -h * h;                                           \
          const float e  = EXP2F(un);                                        \
          const float gg = fmaf(un, p1.z, p1.w);                             \
          A.y = fmaf(gg, e, A.y); }                                          \
        { const float h  = fmaf((xs), p2.x, p2.y);                           \
          const float un = -h * h;                                           \
          const float e  = EXP2F(un);                                        \
          const float gg = fmaf(un, p2.z, p2.w);                             \
          A.z = fmaf(gg, e, A.z); }                                          \
        { const float h  = fmaf((xs), p3.x, p3.y);                           \
          const float un = -h * h;                                           \
          const float e  = EXP2F(un);                                        \
          const float gg = fmaf(un, p3.z, p3.w);                             \
          A.w = fmaf(gg, e, A.w); }                                          \
    }

    #pragma unroll 2
    for (int ii = 0; ii < KIT; ++ii) {
        const float4 p0 = Lp[ii][0 * 16 + oq];   // k-planes: contiguous lanes
        const float4 p1 = Lp[ii][1 * 16 + oq];
        const float4 p2 = Lp[ii][2 * 16 + oq];
        const float4 p3 = Lp[ii][3 * 16 + oq];
        const float4 xA = *reinterpret_cast<const float4*>(&Lx[ii][bq * 8 + 0]);
        const float4 xB = *reinterpret_cast<const float4*>(&Lx[ii][bq * 8 + 4]);
        EVQ(xA.x, a[0]);
        EVQ(xA.y, a[1]);
        EVQ(xA.z, a[2]);
        EVQ(xA.w, a[3]);
        EVQ(xB.x, a[4]);
        EVQ(xB.y, a[5]);
        EVQ(xB.z, a[6]);
        EVQ(xB.w, a[7]);
    }
#undef EVQ

    // store: a[r].k is o = o0 + oq*4 + k  => contiguous float4 at o0+oq*4
    #pragma unroll
    for (int r = 0; r < 8; ++r) {
        const size_t base = ((size_t)iz * B_ + b0 + bq * 8 + r) * O_ + o0 + oq * 4;
        *reinterpret_cast<float4*>(&pY[base]) = a[r];
    }
}
#endif // HAVE_DMA

// ---------------------------------------------------------------------------
// kanZ (proven R7 kernel) — fallback if DMA builtin unavailable.
// ---------------------------------------------------------------------------
__global__ __launch_bounds__(256) void kanZ(
    const float* __restrict__ x, const float* __restrict__ scale,
    const float* __restrict__ bias, const float* __restrict__ weight,
    float* __restrict__ pY)
{
    __shared__ float Lx[KI][LXS];
    __shared__ float Lp[KI][TO][4];

    const int fid = blockIdx.x;
    const int xcd = fid & 7;
    const int seq = fid >> 3;
    const int ot  = xcd * 4 + (seq & 3);
    const int by  = (seq >> 2) & 7;
    const int iz  = seq >> 5;

    const int o0 = ot * TO;
    const int b0 = by * TB;
    const int z0 = iz * NIZ;

    const int t   = threadIdx.x;
    const int to  = t & (TO - 1);
    const int tb4 = t >> 4;
    const int lb  = t >> 2;
    const int lq  = t & 3;
    const int li  = t >> 4;
    const int lo  = t & 15;

    float acc0 = 0.f, acc1 = 0.f, acc2 = 0.f, acc3 = 0.f;

    for (int ch = 0; ch < NCHZ; ++ch) {
        const int i0 = z0 + ch * KI;
        const float4 xv = *reinterpret_cast<const float4*>(
            &x[(size_t)(b0 + lb) * I_ + i0 + lq * 4]);
        const int pidx = (i0 + li) * O_ + o0 + lo;
        const float sc = scale[pidx];
        const float bi = bias[pidx];
        const float w  = weight[pidx];

        __syncthreads();
        Lx[lq * 4 + 0][lb] = xv.x;
        Lx[lq * 4 + 1][lb] = xv.y;
        Lx[lq * 4 + 2][lb] = xv.z;
        Lx[lq * 4 + 3][lb] = xv.w;
        const float c = SQH * __builtin_amdgcn_rcpf(sc);
        Lp[li][lo][0] = c;
        Lp[li][lo][1] = -bi * c;
        Lp[li][lo][2] = MN_ * w;
        Lp[li][lo][3] = NN_ * w;
        __syncthreads();

        #pragma unroll
        for (int ii = 0; ii < KI; ++ii) {
            const float4 p  = *reinterpret_cast<const float4*>(&Lp[ii][to][0]);
            const float4 x4 = *reinterpret_cast<const float4*>(&Lx[ii][tb4 * 4]);
            {
                const float h  = fmaf(x4.x, p.x, p.y);
                const float un = -h * h;
                const float e  = EXP2F(un);
                const float gg = fmaf(un, p.z, p.w);
                acc0 = fmaf(gg, e, acc0);
            }
            {
                const float h  = fmaf(x4.y, p.x, p.y);
                const float un = -h * h;
                const float e  = EXP2F(un);
                const float gg = fmaf(un, p.z, p.w);
                acc1 = fmaf(gg, e, acc1);
            }
            {
                const float h  = fmaf(x4.z, p.x, p.y);
                const float un = -h * h;
                const float e  = EXP2F(un);
                const float gg = fmaf(un, p.z, p.w);
                acc2 = fmaf(gg, e, acc2);
            }
            {
                const float h  = fmaf(x4.w, p.x, p.y);
                const float un = -h * h;
                const float e  = EXP2F(un);
                const float gg = fmaf(un, p.z, p.w);
                acc3 = fmaf(gg, e, acc3);
            }
        }
    }

    const size_t base = ((size_t)iz * B_ + b0 + tb4 * 4) * O_ + o0 + to;
    pY[base + 0 * O_] = acc0;
    pY[base + 1 * O_] = acc1;
    pY[base + 2 * O_] = acc2;
    pY[base + 3 * O_] = acc3;
}

// ---------------------------------------------------------------------------
// K2: fused NZ-partial combine + BatchNorm stats + apply. 128 blocks, 4 o's
// each; o<->XCD mapping matches the producer so pY reads hit the local L2.
// ---------------------------------------------------------------------------
template <int NZ>
__global__ __launch_bounds__(256) void comb_bn(
    const float* __restrict__ pY,
    const float* __restrict__ gamma, const float* __restrict__ beta,
    float* __restrict__ y)
{
    __shared__ float Ws[4][8];
    __shared__ float Ac[8];

    const int bid = blockIdx.x;                       // 0..127
    const int o4  = (bid & 7) * 64 + (bid >> 3) * 4;  // XCD k owns o [64k,64k+64)
    const int t   = threadIdx.x;

    float4 v[2];
    float sx = 0.f, sy = 0.f, sz = 0.f, sw = 0.f;
    float qx = 0.f, qy = 0.f, qz = 0.f, qw = 0.f;
    #pragma unroll
    for (int r = 0; r < 2; ++r) {
        const int b = t + 256 * r;
        const size_t base = (size_t)b * O_ + o4;
        float4 a = *reinterpret_cast<const float4*>(&pY[base]);
        #pragma unroll
        for (int z = 1; z < NZ; ++z) {
            const float4 p = *reinterpret_cast<const float4*>(&pY[(size_t)z * BO_ + base]);
            a.x += p.x; a.y += p.y; a.z += p.z; a.w += p.w;
        }
        v[r] = a;
        sx += a.x; sy += a.y; sz += a.z; sw += a.w;
        qx += a.x * a.x; qy += a.y * a.y; qz += a.z * a.z; qw += a.w * a.w;
    }

    #pragma unroll
    for (int m = 1; m < 64; m <<= 1) {
        sx += __shfl_xor(sx, m); sy += __shfl_xor(sy, m);
        sz += __shfl_xor(sz, m); sw += __shfl_xor(sw, m);
        qx += __shfl_xor(qx, m); qy += __shfl_xor(qy, m);
        qz += __shfl_xor(qz, m); qw += __shfl_xor(qw, m);
    }
    if ((t & 63) == 0) {
        const int wv = t >> 6;
        Ws[wv][0] = sx; Ws[wv][1] = sy; Ws[wv][2] = sz; Ws[wv][3] = sw;
        Ws[wv][4] = qx; Ws[wv][5] = qy; Ws[wv][6] = qz; Ws[wv][7] = qw;
    }
    __syncthreads();
    if (t < 4) {
        const float s  = Ws[0][t]     + Ws[1][t]     + Ws[2][t]     + Ws[3][t];
        const float q  = Ws[0][t + 4] + Ws[1][t + 4] + Ws[2][t + 4] + Ws[3][t + 4];
        const float mean = s * (1.0f / B_);
        const float var  = q * (1.0f / B_) - mean * mean;
        const float inv  = rsqrtf(var + BN_EPS);
        const float a = gamma[o4 + t] * inv;
        Ac[t]     = a;
        Ac[t + 4] = fmaf(-mean, a, beta[o4 + t]);
    }
    __syncthreads();

    const float4 a4 = *reinterpret_cast<const float4*>(&Ac[0]);
    const float4 c4 = *reinterpret_cast<const float4*>(&Ac[4]);
    #pragma unroll
    for (int r = 0; r < 2; ++r) {
        const int b = t + 256 * r;
        float4 o;
        o.x = fmaf(v[r].x, a4.x, c4.x);
        o.y = fmaf(v[r].y, a4.y, c4.y);
        o.z = fmaf(v[r].z, a4.z, c4.z);
        o.w = fmaf(v[r].w, a4.w, c4.w);
        *reinterpret_cast<float4*>(&y[(size_t)b * O_ + o4]) = o;
    }
}

// ---------------------------------------------------------------------------

extern "C" void kernel_launch(void* const* d_in, const int* in_sizes, int n_in,
                              void* d_out, int out_size, void* d_ws, size_t ws_size,
                              hipStream_t stream) {
    const float* x      = (const float*)d_in[0];
    const float* scale  = (const float*)d_in[1];
    const float* bias   = (const float*)d_in[2];
    const float* weight = (const float*)d_in[3];
    const float* gamma  = (const float*)d_in[4];
    const float* beta   = (const float*)d_in[5];
    float* out = (float*)d_out;

    const size_t pYT_b = (size_t)ZT * BO_ * sizeof(float);    // 32 MB
    const size_t pp_b  = (size_t)IO_ * sizeof(float4);        // 4 MB
    const size_t xT_b  = (size_t)B_ * I_ * sizeof(float);     // 1 MB
    const size_t needT = pYT_b + pp_b + xT_b;                 // 37 MB
    const size_t pYZ_b = (size_t)ZN * BO_ * sizeof(float);    // 8 MB

#ifdef HAVE_DMA
    if (ws_size >= needT) {
        float*  pY  = (float*)d_ws;
        float4* ppS = (float4*)((char*)d_ws + pYT_b);
        float*  xT  = (float*)((char*)d_ws + pYT_b + pp_b);

        pack_px<<<IO_ / 256 + 64, 256, 0, stream>>>(x, scale, bias, weight, ppS, xT);
        kanT<<<8 * 4 * ZT, 256, 0, stream>>>(ppS, xT, pY);             // 1024 blocks
        comb_bn<ZT><<<O_ / 4, 256, 0, stream>>>(pY, gamma, beta, out); // 128 blocks
        return;
    }
#endif
    if (ws_size >= pYZ_b) {
        float* pY = (float*)d_ws;
        kanZ<<<32 * 8 * 8, 256, 0, stream>>>(x, scale, bias, weight, pY);
        comb_bn<ZN><<<O_ / 4, 256, 0, stream>>>(pY, gamma, beta, out);
    }
}